// Round 2
// baseline (303.541 us; speedup 1.0000x reference)
//
#include <hip/hip_runtime.h>
#include <hip/hip_bf16.h>

// Fused Conv3d(3->16,k=3,valid) + conv_b + ReLU + maxpool2x2x2
// + spatial mean(fp32) + /2 + bias + channel-sum  ->  out[32] fp32.
//
// R11: break the per-iteration latency serialization.
//  - Loop barrier is inline-asm {s_waitcnt lgkmcnt(0); s_barrier} — does NOT
//    drain vmcnt, so global prefetch loads stay in flight across barriers
//    (plain __syncthreads compiles to vmcnt(0) drain = ~900cy HBM stall/iter).
//    Safety: each wave drains its own ds_writes AND prior ds_reads via
//    lgkmcnt(0) before the barrier -> producer/consumer + WAR both ordered.
//  - Global prefetch depth 2 (two register sets, dp unrolled by 2, static
//    indexing): ~2 iters of latency cover for HBM loads. +12 VGPR, same
//    occupancy bucket (65-128 VGPR -> 4 waves/SIMD, 2 blocks/CU).
//  - XCD-aware bijective swizzle (2016 = 8*252): each XCD owns 4 b-values x
//    all 63 hp, so hp-neighbors sharing the 2-row h-halo hit the same L2.
//  (R10 carried forward): ci-fast K packing -> 1 ds_write_b64/row staging,
//  conflict-shaped (dr&1 split across wave halves), pool via DPP quad_perm,
//  double-buffered LDS, one barrier/iter.
//  MFMA m32n32k16: M=(dd,ch), N=(wi,hh) cols col=2*wi+hh, K=(dl,ci),
//  kw via row-shifted B; 9 MFMAs/wave/iter, ONE acc.
//  D (m74/m101): col=lane&31, row=(reg&3)+8*(reg>>2)+4*(lane>>5).

typedef __attribute__((ext_vector_type(8)))  short  short8;
typedef __attribute__((ext_vector_type(4)))  float  floatx4;
typedef __attribute__((ext_vector_type(16))) float  floatx16;

__device__ __forceinline__ short f2bf(float f) {
    unsigned u = __builtin_bit_cast(unsigned, f);
    unsigned r = (u + 0x7FFFu + ((u >> 16) & 1u)) >> 16;
    return (short)r;
}

__device__ __forceinline__ unsigned pkbf2(float a, float b) {
    __hip_bfloat162 h = __float22bfloat162_rn(float2{a, b});  // v_cvt_pk_bf16_f32
    unsigned r;
    __builtin_memcpy(&r, &h, 4);
    return r;
}

template <int CTRL>
__device__ __forceinline__ float dpp_max(float v) {
    int x = __builtin_bit_cast(int, v);
    int y = __builtin_amdgcn_mov_dpp(x, CTRL, 0xF, 0xF, true);
    return fmaxf(v, __builtin_bit_cast(float, y));
}

// LDS-only barrier: drain DS ops, leave global loads in flight (no vmcnt!).
#define BAR() asm volatile("s_waitcnt lgkmcnt(0)\n\ts_barrier" ::: "memory")

// ---- init: wtab[f=kh*3+kw][lane][8] zero-padded A-frags + out = bias sums ----
__global__ void init_kernel(const float* __restrict__ wg,
                            const float* __restrict__ biasg,
                            short* __restrict__ wtab,   // d_ws: 9*64*8 bf16 = 9216 B
                            float* __restrict__ out)    // [32]
{
    const int t = threadIdx.x;               // 0..575
    if (t < 576) {
        const int lane = t & 63, f = t >> 6;
        const int kh = f / 3, kw = f % 3;
        const int m = lane & 31, hs = lane >> 5;
        const int dd = m >> 4, ch = m & 15;
        short8 v;
        #pragma unroll
        for (int j = 0; j < 8; ++j) {
            const int s = hs * 8 + j;        // k-slot: dl = s>>2, ci = s&3 (ci-fast)
            const int dl = s >> 2, ci = s & 3;
            const int kd = dl - dd;
            v[j] = (ci < 3 && kd >= 0 && kd < 3)
                 ? f2bf(wg[ch * 81 + ci * 27 + kd * 9 + kh * 3 + kw]) : (short)0;
        }
        ((short8*)wtab)[f * 64 + lane] = v;
    }
    if (t < 32) {
        float s = 0.f;
        #pragma unroll
        for (int cc = 0; cc < 16; ++cc) s += biasg[cc];
        out[t] = s;   // conv blocks atomicAdd on top
    }
}

__global__ __launch_bounds__(512, 4) void fused_conv_pool_reduce(
    const float* __restrict__ xg,    // f32 [32][3][32][128][128]
    const short* __restrict__ wtab,  // bf16 frag table in d_ws
    const float* __restrict__ cbg,   // f32 [16]
    float* __restrict__ out)         // f32 [32]
{
    __shared__ __align__(16) short rawT[2 * 130 * 64];  // 33,280 B (double buffer)
    __shared__ float wsums[8];

    // ---- XCD-aware bijective swizzle: 2016 blocks = 8 XCDs x 252 ----
    // Each XCD gets 252 consecutive ids = 4 full b x all 63 hp -> the hp
    // h-halo (2 shared rows) is reused within one XCD's L2.
    const int lin = blockIdx.y * 63 + blockIdx.x;      // 0..2015
    const int nl  = (lin & 7) * 252 + (lin >> 3);
    const int hp  = nl % 63;
    const int b   = nl / 63;

    const int tid = threadIdx.x;  // 0..511
    const int lane = tid & 63;
    const int wv   = tid >> 6;    // wave = 16-wide w tile
    const int hs   = lane >> 5;

    // ---- resident A-frags (36 VGPR) and conv-bias values ----
    short8 af[9];
    #pragma unroll
    for (int f = 0; f < 9; ++f) af[f] = ((const short8*)wtab)[f * 64 + lane];
    float cb8[8];
    #pragma unroll
    for (int r = 0; r < 8; ++r) cb8[r] = cbg[(r & 3) + 8 * (r >> 2) + 4 * hs];

    // ---- zero rows 128/129 of both buffers (once) ----
    if (tid < 64)
        *(unsigned long long*)((char*)rawT + (tid >> 5) * 16640 + 16384 + (tid & 31) * 8) = 0ULL;

    // ---- dp-invariant addresses ----
    const int w4 = tid & 31, dr = (tid >> 5) & 3, hr = (tid >> 7) & 3;
    int waddr[4];
    {
        const int chunkL = hr * 2 + (dr >> 1);
        #pragma unroll
        for (int i = 0; i < 4; ++i) {
            const int row = 4 * w4 + i;
            const int phys = chunkL ^ ((row ^ (row >> 3)) & 7);
            waddr[i] = row * 128 + phys * 16 + (dr & 1) * 8;
        }
    }
    const int wi = (lane >> 1) & 15, hh = lane & 1;
    int raddr[3][3];
    #pragma unroll
    for (int kh = 0; kh < 3; ++kh) {
        #pragma unroll
        for (int kw = 0; kw < 3; ++kw) {
            const int row = wv * 16 + wi + kw;
            const int phys = ((hh + kh) * 2 + hs) ^ ((row ^ (row >> 3)) & 7);
            raddr[kh][kw] = row * 128 + phys * 16;
        }
    }

    float vsum = 0.f;

    auto stage = [&](const floatx4& c0, const floatx4& c1, const floatx4& c2, int bofs) {
        #pragma unroll
        for (int i = 0; i < 4; ++i) {
            uint2 pk;
            pk.x = pkbf2(c0[i], c1[i]);        // [bf(ci0), bf(ci1)]
            pk.y = pkbf2(c2[i], 0.0f);         // [bf(ci2), 0-pad]
            *(uint2*)((char*)rawT + bofs + waddr[i]) = pk;
        }
    };
    auto compute = [&](int bofs) {
        floatx16 acc = {0.f,0.f,0.f,0.f,0.f,0.f,0.f,0.f,
                        0.f,0.f,0.f,0.f,0.f,0.f,0.f,0.f};
        #pragma unroll
        for (int kh = 0; kh < 3; ++kh) {
            #pragma unroll
            for (int kw = 0; kw < 3; ++kw) {
                const short8 bf = *(const short8*)((char*)rawT + bofs + raddr[kh][kw]);
                acc = __builtin_amdgcn_mfma_f32_32x32x16_bf16(af[kh * 3 + kw], bf, acc, 0, 0, 0);
            }
        }
        #pragma unroll
        for (int r = 0; r < 8; ++r) {
            float v = fmaxf(fmaxf(acc[r], acc[r + 8]) + cb8[r], 0.f);
            v = dpp_max<0xB1>(v);   // pool over hh     (lane ^ 1)
            v = dpp_max<0x4E>(v);   // pool over w pair (lane ^ 2)
            vsum += v;
        }
    };

    // ---- prefetch depth 2: sets A (even dp) and B (odd dp) ----
    const float* src = xg + ((size_t)b * 96 + dr) * 16384 + (2 * hp + hr) * 128 + 4 * w4;
    floatx4 a0 = *(const floatx4*)(src);
    floatx4 a1 = *(const floatx4*)(src + 524288);
    floatx4 a2 = *(const floatx4*)(src + 1048576);
    src += 32768;
    floatx4 b0 = *(const floatx4*)(src);
    floatx4 b1 = *(const floatx4*)(src + 524288);
    floatx4 b2 = *(const floatx4*)(src + 1048576);
    src += 32768;   // now points at dp=2

    for (int dpb = 0; dpb < 7; ++dpb) {
        // even dp = 2*dpb: consume set A into buf0, reload A <- dp+2
        stage(a0, a1, a2, 0);
        a0 = *(const floatx4*)(src);
        a1 = *(const floatx4*)(src + 524288);
        a2 = *(const floatx4*)(src + 1048576);
        src += 32768;
        BAR();
        compute(0);

        // odd dp = 2*dpb+1: consume set B into buf1, reload B <- dp+2 (if any)
        stage(b0, b1, b2, 16640);
        if (dpb < 6) {
            b0 = *(const floatx4*)(src);
            b1 = *(const floatx4*)(src + 524288);
            b2 = *(const floatx4*)(src + 1048576);
            src += 32768;
        }
        BAR();
        compute(16640);
    }
    // tail dp = 14
    stage(a0, a1, a2, 0);
    BAR();
    compute(0);

    // valid lanes: quad leaders (hh==0, wi even), pooled pair base <= 124 (conv W=126)
    const bool okl = ((lane & 3) == 0) && (wv * 16 + wi <= 124);
    float s = okl ? vsum : 0.f;
    #pragma unroll
    for (int off = 1; off < 64; off <<= 1) s += __shfl_xor(s, off, 64);

    if (lane == 0) wsums[wv] = s;
    __syncthreads();
    if (tid == 0) {
        float bs = 0.f;
        #pragma unroll
        for (int i = 0; i < 8; ++i) bs += wsums[i];
        atomicAdd(&out[b], bs * (1.0f / 119070.0f));   // /(15*63*63)/2
    }
}

extern "C" void kernel_launch(void* const* d_in, const int* in_sizes, int n_in,
                              void* d_out, int out_size, void* d_ws, size_t ws_size,
                              hipStream_t stream) {
    const float* x      = (const float*)d_in[0];
    const float* conv_w = (const float*)d_in[1];
    const float* conv_b = (const float*)d_in[2];
    const float* bias   = (const float*)d_in[3];
    float* out = (float*)d_out;
    short* wtab = (short*)d_ws;   // 9216 B

    init_kernel<<<1, 576, 0, stream>>>(conv_w, bias, wtab, out);
    dim3 grid(63, 32);  // (hp, b) pre-swizzle
    fused_conv_pool_reduce<<<grid, 512, 0, stream>>>(x, wtab, conv_b, out);
}

// Round 3
// 285.746 us; speedup vs baseline: 1.0623x; 1.0623x over previous
//
#include <hip/hip_runtime.h>
#include <hip/hip_bf16.h>

// Fused Conv3d(3->16,k=3,valid) + conv_b + ReLU + maxpool2x2x2
// + spatial mean(fp32) + /2 + bias + channel-sum  ->  out[32] fp32.
//
// R12: issue-rate diet (kernel is pipe/issue-bound, not latency-bound: R11's
// latency fixes were neutral).
//  - OPERAND SWAP: acc = mfma(spatial, weights) -> M=(wi,hh) spatial rows in
//    regs, N=(ch,dd) cols on lanes (col=2ch+dd). Each lane's acc[4a..4a+3] is
//    one full 2x2 h/w pool window -> pooled IN-REGISTER (3 v_max); dd-pool is
//    one DPP(^1); +conv_b+relu once per POOLED value (monotone). Epilogue
//    64 -> 32 VALU/lane/iter, no serial DPP chains. Validity via fmaf mask.
//  - D-PLANE ROTATION: LDS k-slots keyed by ABSOLUTE dl = d&3. Per iter stage
//    only the 2 NEW planes (pair dp+2) into the buffer freed 2 iters ago.
//    Odd-dp slot rotation (^8 slots = chunk bit0) = addr^16; buffer select
//    = ((dp+hs)>>1)&1 per lane-half. Staging work halves (4 cvt + 2 b64
//    writes + 3 float2 loads per thread-iter). WAR spans 2 barriers.
//  (kept) ci-fast slots, XOR bank swizzle, lgkm-only BAR (no vmcnt drain),
//  XCD-aware bijective block swizzle, 1 barrier/iter.
//  MFMA m32n32k16, D: col=lane&31, row=(reg&3)+8*(reg>>2)+4*(lane>>5).

typedef __attribute__((ext_vector_type(8)))  short  short8;
typedef __attribute__((ext_vector_type(2)))  float  floatx2;
typedef __attribute__((ext_vector_type(4)))  float  floatx4;
typedef __attribute__((ext_vector_type(16))) float  floatx16;

__device__ __forceinline__ short f2bf(float f) {
    unsigned u = __builtin_bit_cast(unsigned, f);
    unsigned r = (u + 0x7FFFu + ((u >> 16) & 1u)) >> 16;
    return (short)r;
}

__device__ __forceinline__ unsigned pkbf2(float a, float b) {
    __hip_bfloat162 h = __float22bfloat162_rn(float2{a, b});  // v_cvt_pk_bf16_f32
    unsigned r;
    __builtin_memcpy(&r, &h, 4);
    return r;
}

template <int CTRL>
__device__ __forceinline__ float dpp_max(float v) {
    int x = __builtin_bit_cast(int, v);
    int y = __builtin_amdgcn_mov_dpp(x, CTRL, 0xF, 0xF, true);
    return fmaxf(v, __builtin_bit_cast(float, y));
}

// LDS-only barrier: drain DS ops, leave global loads in flight (no vmcnt).
#define BAR() asm volatile("s_waitcnt lgkmcnt(0)\n\ts_barrier" ::: "memory")

#define BUFSZ 16640

// ---- init: wtab[f=kh*3+kw][lane][8] zero-padded B-frags + out = bias sums ----
// B operand now: col n = lane&31 = 2*ch + dd; k-slot rel = (lane>>5)*8+j,
// dl_rel = slot>>2, ci = slot&3 (ci-fast); kd = dl_rel - dd.
__global__ void init_kernel(const float* __restrict__ wg,
                            const float* __restrict__ biasg,
                            short* __restrict__ wtab,   // d_ws: 9*64*8 bf16 = 9216 B
                            float* __restrict__ out)    // [32]
{
    const int t = threadIdx.x;               // 0..575
    if (t < 576) {
        const int lane = t & 63, f = t >> 6;
        const int kh = f / 3, kw = f % 3;
        const int m = lane & 31, hs = lane >> 5;
        const int ch = m >> 1, dd = m & 1;   // col = 2*ch + dd
        short8 v;
        #pragma unroll
        for (int j = 0; j < 8; ++j) {
            const int s = hs * 8 + j;        // k-slot: dl_rel = s>>2, ci = s&3
            const int dl = s >> 2, ci = s & 3;
            const int kd = dl - dd;
            v[j] = (ci < 3 && kd >= 0 && kd < 3)
                 ? f2bf(wg[ch * 81 + ci * 27 + kd * 9 + kh * 3 + kw]) : (short)0;
        }
        ((short8*)wtab)[f * 64 + lane] = v;
    }
    if (t < 32) {
        float s = 0.f;
        #pragma unroll
        for (int cc = 0; cc < 16; ++cc) s += biasg[cc];
        out[t] = s;   // conv blocks atomicAdd on top
    }
}

__global__ __launch_bounds__(512, 4) void fused_conv_pool_reduce(
    const float* __restrict__ xg,    // f32 [32][3][32][128][128]
    const short* __restrict__ wtab,  // bf16 frag table in d_ws
    const float* __restrict__ cbg,   // f32 [16]
    float* __restrict__ out)         // f32 [32]
{
    __shared__ __align__(16) short rawT[2 * 130 * 64];  // 33,280 B (2 buffers)
    __shared__ float wsums[8];

    // XCD-aware bijective swizzle: 2016 = 8 XCDs x 252 (4 b x 63 hp each).
    const int lin = blockIdx.y * 63 + blockIdx.x;      // 0..2015
    const int nl  = (lin & 7) * 252 + (lin >> 3);
    const int hp  = nl % 63;
    const int b   = nl / 63;

    const int tid = threadIdx.x;  // 0..511
    const int lane = tid & 63;
    const int wv   = tid >> 6;    // wave = 16-wide w tile
    const int hs   = lane >> 5;

    // ---- resident B-frags (36 VGPR), conv-bias, validity masks ----
    short8 af[9];
    #pragma unroll
    for (int f = 0; f < 9; ++f) af[f] = ((const short8*)wtab)[f * 64 + lane];
    const float cbv = cbg[(lane >> 1) & 15];   // ch = (lane&31)>>1
    float maskA[4];
    #pragma unroll
    for (int a = 0; a < 4; ++a) {
        const bool ok = ((lane & 1) == 0) && (wv * 8 + 2 * a + hs <= 62);
        maskA[a] = ok ? 1.0f : 0.0f;
    }

    // ---- zero rows 128/129 of both buffers (once) ----
    if (tid < 64)
        *(unsigned long long*)((char*)rawT + (tid >> 5) * BUFSZ + 16384 + (tid & 31) * 8) = 0ULL;

    #define SWZ(r) (((r) ^ ((r) >> 3)) & 7)

    // ---- per-iter stage map: 2 planes (pair dp+2), 2 rows x 8B per thread ----
    const int w4 = tid & 31, dr2 = (tid >> 5) & 1, rr = (tid >> 6) & 1, hr2 = (tid >> 7) & 3;
    int waddr2[2];
    #pragma unroll
    for (int j = 0; j < 2; ++j) {
        const int row = 2 * w4 + 64 * rr + j;
        waddr2[j] = row * 128 + ((hr2 * 2) ^ SWZ(row)) * 16 + dr2 * 8;  // ^ (p<<4) at runtime
    }

    // ---- read map (A = spatial): row = wv*16 + wi + kw, chunk = (hh+kh)*2 + hs ----
    const int wi = (lane >> 1) & 15, hh = lane & 1;
    int raddr[3][3];
    #pragma unroll
    for (int kh = 0; kh < 3; ++kh) {
        #pragma unroll
        for (int kw = 0; kw < 3; ++kw) {
            const int row = wv * 16 + wi + kw;
            const int phys = ((hh + kh) * 2 + hs) ^ SWZ(row);
            raddr[kh][kw] = row * 128 + phys * 16;   // ^ (p<<4) + rbuf*BUFSZ at runtime
        }
    }

    // ---- prologue: stage pairs 0,1 (planes 0..3) into buffer 0 ----
    {
        const int w4p = tid & 31, drp = (tid >> 5) & 3, hrp = (tid >> 7) & 3;
        const float* srcP = xg + ((size_t)b * 96 + drp) * 16384 + (2 * hp + hrp) * 128 + 4 * w4p;
        const floatx4 c0 = *(const floatx4*)(srcP);
        const floatx4 c1 = *(const floatx4*)(srcP + 524288);
        const floatx4 c2 = *(const floatx4*)(srcP + 1048576);
        const int chunkL = hrp * 2 + (drp >> 1);
        #pragma unroll
        for (int i = 0; i < 4; ++i) {
            const int row = 4 * w4p + i;
            const int ad = row * 128 + (chunkL ^ SWZ(row)) * 16 + (drp & 1) * 8;
            uint2 pk;
            pk.x = pkbf2(c0[i], c1[i]);
            pk.y = pkbf2(c2[i], 0.0f);
            *(uint2*)((char*)rawT + ad) = pk;
        }
    }

    // ---- prologue prefetch: pair 2 (planes 4,5), float2 per ci ----
    const float* src2 = xg + ((size_t)b * 96 + 4 + dr2) * 16384
                      + (2 * hp + hr2) * 128 + 2 * w4 + 64 * rr;
    floatx2 A0 = *(const floatx2*)(src2);
    floatx2 A1 = *(const floatx2*)(src2 + 524288);
    floatx2 A2 = *(const floatx2*)(src2 + 1048576);

    float vsum = 0.f;
    for (int dp = 0; dp < 15; ++dp) {
        const int p16 = (dp & 1) << 4;
        if (dp <= 13) {
            // stage pair dp+2 into buffer ((dp>>1)+1)&1, chunk-group = dp&1
            const int bw = (((dp >> 1) + 1) & 1) * BUFSZ;
            uint2 pk0, pk1;
            pk0.x = pkbf2(A0[0], A1[0]); pk0.y = pkbf2(A2[0], 0.0f);
            pk1.x = pkbf2(A0[1], A1[1]); pk1.y = pkbf2(A2[1], 0.0f);
            *(uint2*)((char*)rawT + bw + (waddr2[0] ^ p16)) = pk0;
            *(uint2*)((char*)rawT + bw + (waddr2[1] ^ p16)) = pk1;
            if (dp <= 12) {     // prefetch pair dp+3 (full-iter latency cover)
                src2 += 32768;
                A0 = *(const floatx2*)(src2);
                A1 = *(const floatx2*)(src2 + 524288);
                A2 = *(const floatx2*)(src2 + 1048576);
            }
        }
        BAR();   // LDS-only; global loads stay in flight

        // read buffer per lane-half: pair (dp+hs) -> buffer ((dp+hs)>>1)&1
        const int roff = (((dp + hs) >> 1) & 1) * BUFSZ;

        floatx16 acc = {0.f,0.f,0.f,0.f,0.f,0.f,0.f,0.f,
                        0.f,0.f,0.f,0.f,0.f,0.f,0.f,0.f};
        #pragma unroll
        for (int kh = 0; kh < 3; ++kh) {
            #pragma unroll
            for (int kw = 0; kw < 3; ++kw) {
                const short8 bf = *(const short8*)((char*)rawT + roff + (raddr[kh][kw] ^ p16));
                acc = __builtin_amdgcn_mfma_f32_32x32x16_bf16(bf, af[kh * 3 + kw], acc, 0, 0, 0);
            }
        }
        // epilogue: acc[4a..4a+3] = one 2x2 h/w window (in-reg max),
        // dd-pool = DPP ^1, then +cb, relu, masked accumulate.
        #pragma unroll
        for (int a = 0; a < 4; ++a) {
            float m01 = fmaxf(acc[4 * a],     acc[4 * a + 1]);
            float m23 = fmaxf(acc[4 * a + 2], acc[4 * a + 3]);
            float m   = fmaxf(m01, m23);
            m = dpp_max<0xB1>(m);                 // pool over dd (lane ^ 1)
            const float v = fmaxf(m + cbv, 0.f);  // +conv_b, relu (post-pool: monotone)
            vsum = fmaf(maskA[a], v, vsum);
        }
    }

    // mask already zeroes invalid lanes/groups: plain full-wave sum
    float s = vsum;
    #pragma unroll
    for (int off = 1; off < 64; off <<= 1) s += __shfl_xor(s, off, 64);

    if (lane == 0) wsums[wv] = s;
    __syncthreads();
    if (tid == 0) {
        float bs = 0.f;
        #pragma unroll
        for (int i = 0; i < 8; ++i) bs += wsums[i];
        atomicAdd(&out[b], bs * (1.0f / 119070.0f));   // /(15*63*63)/2
    }
}

extern "C" void kernel_launch(void* const* d_in, const int* in_sizes, int n_in,
                              void* d_out, int out_size, void* d_ws, size_t ws_size,
                              hipStream_t stream) {
    const float* x      = (const float*)d_in[0];
    const float* conv_w = (const float*)d_in[1];
    const float* conv_b = (const float*)d_in[2];
    const float* bias   = (const float*)d_in[3];
    float* out = (float*)d_out;
    short* wtab = (short*)d_ws;   // 9216 B

    init_kernel<<<1, 576, 0, stream>>>(conv_w, bias, wtab, out);
    dim3 grid(63, 32);  // (hp, b) pre-swizzle
    fused_conv_pool_reduce<<<grid, 512, 0, stream>>>(x, wtab, conv_b, out);
}